// Round 5
// baseline (1021.819 us; speedup 1.0000x reference)
//
#include <hip/hip_runtime.h>

// 3-layer LSTM, B=256, T=2048, H=32, in=64. fp32.
// ONE kernel: 256 blocks x 256 threads (4 waves = 1 per SIMD), pipelined by
// 16-step chunks with skew: w3 feeds xg0 (chunk p), w0 runs L0 recurrence
// (chunk p-1) AND produces xg1 from its own h-broadcast registers, w1 runs L1
// (chunk p-2) and produces xg2, w2 runs L2 (chunk p-3) + final projection.
// Recurrence serial path is pure VALU + one batched ds_bpermute broadcast:
//   hn -> 32x ds_bpermute (h in VGPR pairs) -> 32x v_pk_fma_f32 -> tail.
// No per-step LDS write/read round-trip, no feeder contention on the SIMDs.

typedef float v2f __attribute__((ext_vector_type(2)));

constexpr int T_SEQ  = 2048;
constexpr int HID    = 32;
constexpr int CH     = 16;             // timesteps per chunk
constexpr int NCHUNK = T_SEQ / CH;     // 128
constexpr int NPHASE = NCHUNK + 3;     // skews 0..3

__device__ __forceinline__ float sigmoid_f(float x) { return 1.0f / (1.0f + __expf(-x)); }
__device__ __forceinline__ float tanh_f(float x)    { return 1.0f - 2.0f / (__expf(2.0f * x) + 1.0f); }

#define GLOAD_LDS16(gsrc, ldst)                                                              \
    __builtin_amdgcn_global_load_lds((const __attribute__((address_space(1))) void*)(gsrc), \
                                     (__attribute__((address_space(3))) void*)(ldst),        \
                                     16, 0, 0)
#define KEEPV(x) asm volatile("" : "+v"(x))

// One chunk of LSTM recurrence for one wave. lane l owns gate rows l (A) and
// l+64 (B): lanes<32 -> A=i, B=g(tanh); lanes>=32 -> A=f, B=o.
// hb2[j] = {h[2j], h[2j+1]} broadcast in VGPRs (valid in all lanes).
// If PROD: also emits next layer's xg (W_ih_next . h + b_next) per step.
template<bool PROD>
__device__ __forceinline__ void rec_chunk(int l, int a0v,
    const v2f* __restrict__ xg_in, v2f* __restrict__ xg_out,
    const v2f (&whA)[16], const v2f (&whB)[16],
    const v2f* wiA, const v2f* wiB, float biA, float biB,
    v2f (&hb2)[16], float& c, float& hreg)
{
    // prefetch the whole chunk's xg into registers (one lgkm batch)
    v2f xgr[CH];
#pragma unroll
    for (int tt = 0; tt < CH; ++tt) xgr[tt] = xg_in[tt * 64 + l];

#pragma unroll
    for (int tt = 0; tt < CH; ++tt) {
        // h-dot: 2 gates x 16 pk_fma, 2 chains each
        v2f aA0 = {xgr[tt].x, 0.f}, aA1 = {0.f, 0.f};
        v2f aB0 = {xgr[tt].y, 0.f}, aB1 = {0.f, 0.f};
#pragma unroll
        for (int j = 0; j < 16; j += 2) {
            aA0 = hb2[j]   * whA[j]   + aA0;  aB0 = hb2[j]   * whB[j]   + aB0;
            aA1 = hb2[j+1] * whA[j+1] + aA1;  aB1 = hb2[j+1] * whB[j+1] + aB1;
        }
        const float ga = (aA0.x + aA1.x) + (aA0.y + aA1.y);
        const float gb = (aB0.x + aB1.x) + (aB0.y + aB1.y);

        const float sA = sigmoid_f(ga);
        const float tb = tanh_f(l < 32 ? gb : 0.5f * gb);
        const float vB = (l < 32) ? tb : fmaf(0.5f, tb, 0.5f);   // o via tanh half-arg
        const float fv = __shfl_xor(sA, 32);    // lanes<32 receive f
        const float ov = __shfl_xor(vB, 32);    // lanes<32 receive o
        const float cn = fmaf(fv, c, sA * vB);  // valid in lanes<32 (hi lanes benign)
        const float hn = ov * tanh_f(cn);
        c = cn; hreg = hn;

        // broadcast h(t): h[k] lives in lane k (k<32) -> 32 bpermute into pairs
        const int hbits = __float_as_int(hn);
#pragma unroll
        for (int j = 0; j < 16; ++j) {
            const float bx = __int_as_float(__builtin_amdgcn_ds_bpermute(a0v + 8*j,     hbits));
            const float by = __int_as_float(__builtin_amdgcn_ds_bpermute(a0v + 8*j + 4, hbits));
            hb2[j] = (v2f){bx, by};
        }

        if constexpr (PROD) {
            // next layer's input pre-activation from the fresh broadcast (off critical path)
            v2f pA = {biA, 0.f}, pB = {biB, 0.f};
#pragma unroll
            for (int j = 0; j < 16; ++j) { pA = hb2[j] * wiA[j] + pA; pB = hb2[j] * wiB[j] + pB; }
            xg_out[tt * 64 + l] = (v2f){pA.x + pA.y, pB.x + pB.y};
        }
    }
}

// feeder for layer 0: xg0[tt][l] = {b0[l] + W_ih0[l].x[tt], b0[l+64] + W_ih0[l+64].x[tt]}
__device__ __forceinline__ void feed0_chunk(int l, const float* __restrict__ xs,
    v2f* __restrict__ xg_out,
    const v2f (&wA)[32], const v2f (&wB)[32], float bAv, float bBv)
{
#pragma unroll
    for (int tt = 0; tt < CH; ++tt) {
        const float4* xt = reinterpret_cast<const float4*>(xs + tt * 64);
        v2f aA0 = {bAv, 0.f}, aA1 = {0.f, 0.f}, aB0 = {bBv, 0.f}, aB1 = {0.f, 0.f};
#pragma unroll
        for (int i = 0; i < 16; ++i) {
            const float4 v = xt[i];
            const v2f lo = {v.x, v.y}, hi = {v.z, v.w};
            aA0 = lo * wA[2*i] + aA0;  aA1 = hi * wA[2*i+1] + aA1;
            aB0 = lo * wB[2*i] + aB0;  aB1 = hi * wB[2*i+1] + aB1;
        }
        xg_out[tt * 64 + l] = (v2f){(aA0.x + aA1.x) + (aA0.y + aA1.y),
                                    (aB0.x + aB1.x) + (aB0.y + aB1.y)};
    }
}

__global__ __launch_bounds__(256, 1)
void lstm3_fused_kernel(const float* __restrict__ x,
    const float* __restrict__ W_ih0, const float* __restrict__ W_hh0, const float* __restrict__ b0,
    const float* __restrict__ W_ih1, const float* __restrict__ W_hh1, const float* __restrict__ b1,
    const float* __restrict__ W_ih2, const float* __restrict__ W_hh2, const float* __restrict__ b2,
    const float* __restrict__ W_out, const float* __restrict__ b_out,
    float* __restrict__ out)
{
    const int bi = blockIdx.x;
    const int w  = threadIdx.x >> 6;
    const int l  = threadIdx.x & 63;

    __shared__ v2f   xg0[2][CH][64];       // 16 KB: gate pre-acts layer 0
    __shared__ v2f   xg1[2][CH][64];       // 16 KB
    __shared__ v2f   xg2[2][CH][64];       // 16 KB
    __shared__ float xstage[2][CH * 64];   // 8 KB: x staging for feeder

    int a0v = 0; asm volatile("" : "+v"(a0v));   // opaque 0: shared bpermute base

    if (w == 0) {                       // ---- L0 recurrence + produce xg1 ----
        v2f whA[16], whB[16], wiA[16], wiB[16];
        const v2f* hA = reinterpret_cast<const v2f*>(W_hh0 + l * 32);
        const v2f* hB = reinterpret_cast<const v2f*>(W_hh0 + (l + 64) * 32);
        const v2f* iA = reinterpret_cast<const v2f*>(W_ih1 + l * 32);
        const v2f* iB = reinterpret_cast<const v2f*>(W_ih1 + (l + 64) * 32);
#pragma unroll
        for (int i = 0; i < 16; ++i) {
            whA[i] = hA[i]; KEEPV(whA[i]); whB[i] = hB[i]; KEEPV(whB[i]);
            wiA[i] = iA[i]; KEEPV(wiA[i]); wiB[i] = iB[i]; KEEPV(wiB[i]);
        }
        const float biA = b1[l], biB = b1[l + 64];
        v2f hb2[16];
#pragma unroll
        for (int i = 0; i < 16; ++i) hb2[i] = (v2f){0.f, 0.f};
        float c = 0.f, hreg = 0.f;
        __syncthreads();
        for (int p = 0; p < NPHASE; ++p) {
            const int ci = p - 1;
            if (ci >= 0 && ci < NCHUNK)
                rec_chunk<true>(l, a0v, &xg0[ci & 1][0][0], &xg1[ci & 1][0][0],
                                whA, whB, wiA, wiB, biA, biB, hb2, c, hreg);
            __syncthreads();
        }
    } else if (w == 1) {                // ---- L1 recurrence + produce xg2 ----
        v2f whA[16], whB[16], wiA[16], wiB[16];
        const v2f* hA = reinterpret_cast<const v2f*>(W_hh1 + l * 32);
        const v2f* hB = reinterpret_cast<const v2f*>(W_hh1 + (l + 64) * 32);
        const v2f* iA = reinterpret_cast<const v2f*>(W_ih2 + l * 32);
        const v2f* iB = reinterpret_cast<const v2f*>(W_ih2 + (l + 64) * 32);
#pragma unroll
        for (int i = 0; i < 16; ++i) {
            whA[i] = hA[i]; KEEPV(whA[i]); whB[i] = hB[i]; KEEPV(whB[i]);
            wiA[i] = iA[i]; KEEPV(wiA[i]); wiB[i] = iB[i]; KEEPV(wiB[i]);
        }
        const float biA = b2[l], biB = b2[l + 64];
        v2f hb2[16];
#pragma unroll
        for (int i = 0; i < 16; ++i) hb2[i] = (v2f){0.f, 0.f};
        float c = 0.f, hreg = 0.f;
        __syncthreads();
        for (int p = 0; p < NPHASE; ++p) {
            const int ci = p - 2;
            if (ci >= 0 && ci < NCHUNK)
                rec_chunk<true>(l, a0v, &xg1[ci & 1][0][0], &xg2[ci & 1][0][0],
                                whA, whB, wiA, wiB, biA, biB, hb2, c, hreg);
            __syncthreads();
        }
    } else if (w == 2) {                // ---- L2 recurrence + projection ----
        v2f whA[16], whB[16];
        const v2f* hA = reinterpret_cast<const v2f*>(W_hh2 + l * 32);
        const v2f* hB = reinterpret_cast<const v2f*>(W_hh2 + (l + 64) * 32);
#pragma unroll
        for (int i = 0; i < 16; ++i) {
            whA[i] = hA[i]; KEEPV(whA[i]); whB[i] = hB[i]; KEEPV(whB[i]);
        }
        const float woutv = W_out[l & 31];
        v2f hb2[16];
#pragma unroll
        for (int i = 0; i < 16; ++i) hb2[i] = (v2f){0.f, 0.f};
        float c = 0.f, hreg = 0.f;
        __syncthreads();
        for (int p = 0; p < NPHASE; ++p) {
            const int ci = p - 3;
            if (ci >= 0 && ci < NCHUNK)
                rec_chunk<false>(l, a0v, &xg2[ci & 1][0][0], nullptr,
                                 whA, whB, nullptr, nullptr, 0.f, 0.f, hb2, c, hreg);
            __syncthreads();
        }
        float s = (l < HID) ? hreg * woutv : 0.f;
#pragma unroll
        for (int off = 32; off; off >>= 1) s += __shfl_xor(s, off);
        if (l == 0) out[bi] = s + b_out[0];
    } else {                            // ---- feeder: xg0 from x ----
        v2f wA[32], wB[32];
        const v2f* pA = reinterpret_cast<const v2f*>(W_ih0 + l * 64);
        const v2f* pB = reinterpret_cast<const v2f*>(W_ih0 + (l + 64) * 64);
#pragma unroll
        for (int i = 0; i < 32; ++i) { wA[i] = pA[i]; KEEPV(wA[i]); wB[i] = pB[i]; KEEPV(wB[i]); }
        const float bAv = b0[l], bBv = b0[l + 64];
        const float* src = x + (size_t)bi * T_SEQ * 64;
        // prologue: stage chunk 0 (barrier below drains vmcnt)
#pragma unroll
        for (int i = 0; i < 4; ++i)
            GLOAD_LDS16(src + i * 256 + l * 4, &xstage[0][i * 256 + l * 4]);
        __syncthreads();
        for (int p = 0; p < NPHASE; ++p) {
            if (p + 1 < NCHUNK) {       // prefetch next chunk; resident by next phase
                const float* ns = src + (size_t)(p + 1) * CH * 64;
                float* dst = &xstage[(p + 1) & 1][0];
#pragma unroll
                for (int i = 0; i < 4; ++i)
                    GLOAD_LDS16(ns + i * 256 + l * 4, dst + i * 256 + l * 4);
            }
            if (p < NCHUNK)
                feed0_chunk(l, xstage[p & 1], &xg0[p & 1][0][0], wA, wB, bAv, bBv);
            __syncthreads();
        }
    }
}

extern "C" void kernel_launch(void* const* d_in, const int* in_sizes, int n_in,
                              void* d_out, int out_size, void* d_ws, size_t ws_size,
                              hipStream_t stream) {
    const float* x      = (const float*)d_in[0];
    const float* W_ih0  = (const float*)d_in[1];
    const float* W_hh0  = (const float*)d_in[2];
    const float* b0     = (const float*)d_in[3];
    const float* W_ih1  = (const float*)d_in[4];
    const float* W_hh1  = (const float*)d_in[5];
    const float* b1     = (const float*)d_in[6];
    const float* W_ih2  = (const float*)d_in[7];
    const float* W_hh2  = (const float*)d_in[8];
    const float* b2     = (const float*)d_in[9];
    const float* W_out  = (const float*)d_in[10];
    const float* b_out  = (const float*)d_in[11];

    lstm3_fused_kernel<<<256, 256, 0, stream>>>(x,
                                                W_ih0, W_hh0, b0,
                                                W_ih1, W_hh1, b1,
                                                W_ih2, W_hh2, b2,
                                                W_out, b_out,
                                                (float*)d_out);
}

// Round 6
// 757.638 us; speedup vs baseline: 1.3487x; 1.3487x over previous
//
#include <hip/hip_runtime.h>

// 3-layer LSTM, B=256, T=2048, H=32, in=64. fp32.
// 256 blocks x 384 threads (6 waves), producer/consumer pipeline by 16-step
// chunks (round-4 structure), with the recurrent h-broadcast done via
// 32x v_readlane into SGPRs (no DS round-trip on the critical path):
//   w3: f0   xg0 = W_ih0@x + b0          (chunk p)
//   w0: rec0 layer-0 recurrence          (chunk p-1)  [SIMD0, shares w/ f1]
//   w4: f1   xg1 = W_ih1@h0 + b1         (chunk p-2)
//   w1: rec1 layer-1 recurrence          (chunk p-3)  [SIMD1, shares w/ f2]
//   w5: f2   xg2 = W_ih2@h1 + b2         (chunk p-4)
//   w2: rec2 layer-2 recurrence + proj   (chunk p-5)  [SIMD2 solo]
// All divisions via v_rcp_f32. h_seq never touches HBM.

typedef float v2f __attribute__((ext_vector_type(2)));

constexpr int T_SEQ  = 2048;
constexpr int CH     = 16;             // timesteps per chunk
constexpr int NCHUNK = T_SEQ / CH;     // 128
constexpr int NPHASE = NCHUNK + 5;     // pipeline depth 6

#define GLOAD_LDS16(gsrc, ldst)                                                              \
    __builtin_amdgcn_global_load_lds((const __attribute__((address_space(1))) void*)(gsrc), \
                                     (__attribute__((address_space(3))) void*)(ldst),        \
                                     16, 0, 0)
#define KEEPV(x) asm volatile("" : "+v"(x))

__device__ __forceinline__ float rcp_f(float x) { return __builtin_amdgcn_rcpf(x); }

// Recurrent chunk with SGPR-resident h (hs[32], wave-uniform via readlane).
// Lane l owns gate rows l (A) and l+64 (B): lanes<32 -> A=i, B=g(tanh);
// lanes>=32 -> A=f, B=o (sigmoid via tanh half-arg: per-lane consts mt,ca,cb).
template<bool RING>
__device__ __forceinline__ void rec_chunk_rl(int l,
    const v2f* __restrict__ xg_in,        // [CH][64] gate pre-activations
    float* __restrict__ ring_out,         // [CH][32] h chunk to next feeder
    const float (&whA)[32], const float (&whB)[32],
    float (&hs)[32], float& c, float& hreg,
    float mt, float ca, float cb)
{
    // prefetch this chunk's xg rows (one lgkm batch, off critical path)
    v2f xgr[CH];
#pragma unroll
    for (int tt = 0; tt < CH; ++tt) xgr[tt] = xg_in[tt * 64 + l];

#pragma unroll
    for (int tt = 0; tt < CH; ++tt) {
        // h-dot: 64 v_fma with SGPR h operand, 4 accumulation chains
        float aA0 = xgr[tt].x, aA1 = 0.f, aB0 = xgr[tt].y, aB1 = 0.f;
#pragma unroll
        for (int k = 0; k < 32; k += 2) {
            aA0 = fmaf(hs[k],     whA[k],     aA0);
            aB0 = fmaf(hs[k],     whB[k],     aB0);
            aA1 = fmaf(hs[k + 1], whA[k + 1], aA1);
            aB1 = fmaf(hs[k + 1], whB[k + 1], aB1);
        }
        const float ga = aA0 + aA1, gb = aB0 + aB1;

        // sA = sigmoid(ga); tb = tanh(gb) [lanes<32] / tanh(gb/2) [lanes>=32]
        const float sA = rcp_f(1.0f + __expf(-ga));
        const float eb = __expf(mt * gb);                   // mt = 2 or 1
        const float tb = fmaf(-2.0f, rcp_f(eb + 1.0f), 1.0f);
        const float vB = fmaf(ca, tb, cb);                  // g or o

        const float fv = __shfl_xor(sA, 32);                // lanes<32: f
        const float ov = __shfl_xor(vB, 32);                // lanes<32: o
        const float cn = fmaf(fv, c, sA * vB);
        const float ec = __expf(2.0f * cn);
        const float hn = ov * fmaf(-2.0f, rcp_f(ec + 1.0f), 1.0f);
        c = cn; hreg = hn;

        if constexpr (RING) { if (l < 32) ring_out[tt * 32 + l] = hn; }

        // h broadcast: 32x readlane -> SGPRs (pure VALU, no DS pipe)
        const int hbits = __float_as_int(hn);
#pragma unroll
        for (int k = 0; k < 32; ++k)
            hs[k] = __int_as_float(__builtin_amdgcn_readlane(hbits, k));
    }
}

// feeder from a 32-wide LDS source (h ring): xg[tt][l] = {bA + Wrow_l.h, bB + Wrow_{l+64}.h}
__device__ __forceinline__ void feed_h_chunk(int l, const float* __restrict__ hr,
    v2f* __restrict__ xg_out, const v2f (&wA)[16], const v2f (&wB)[16],
    float bA, float bB)
{
#pragma unroll
    for (int tt = 0; tt < CH; ++tt) {
        const float4* h4 = reinterpret_cast<const float4*>(hr + tt * 32);
        v2f a0 = {bA, 0.f}, a1 = {0.f, 0.f}, b0 = {bB, 0.f}, b1 = {0.f, 0.f};
#pragma unroll
        for (int i = 0; i < 8; ++i) {
            const float4 v = h4[i];
            const v2f lo = {v.x, v.y}, hi = {v.z, v.w};
            a0 = lo * wA[2*i] + a0;  a1 = hi * wA[2*i+1] + a1;
            b0 = lo * wB[2*i] + b0;  b1 = hi * wB[2*i+1] + b1;
        }
        xg_out[tt * 64 + l] = (v2f){(a0.x + a1.x) + (a0.y + a1.y),
                                    (b0.x + b1.x) + (b0.y + b1.y)};
    }
}

// feeder layer 0 from staged x (64-wide rows)
__device__ __forceinline__ void feed0_chunk(int l, const float* __restrict__ xs,
    v2f* __restrict__ xg_out, const v2f (&wA)[32], const v2f (&wB)[32],
    float bA, float bB)
{
#pragma unroll
    for (int tt = 0; tt < CH; ++tt) {
        const float4* xt = reinterpret_cast<const float4*>(xs + tt * 64);
        v2f a0 = {bA, 0.f}, a1 = {0.f, 0.f}, b0 = {bB, 0.f}, b1 = {0.f, 0.f};
#pragma unroll
        for (int i = 0; i < 16; ++i) {
            const float4 v = xt[i];
            const v2f lo = {v.x, v.y}, hi = {v.z, v.w};
            a0 = lo * wA[2*i] + a0;  a1 = hi * wA[2*i+1] + a1;
            b0 = lo * wB[2*i] + b0;  b1 = hi * wB[2*i+1] + b1;
        }
        xg_out[tt * 64 + l] = (v2f){(a0.x + a1.x) + (a0.y + a1.y),
                                    (b0.x + b1.x) + (b0.y + b1.y)};
    }
}

__global__ __launch_bounds__(384, 2)
void lstm3_rl_kernel(const float* __restrict__ x,
    const float* __restrict__ W_ih0, const float* __restrict__ W_hh0, const float* __restrict__ b0,
    const float* __restrict__ W_ih1, const float* __restrict__ W_hh1, const float* __restrict__ b1,
    const float* __restrict__ W_ih2, const float* __restrict__ W_hh2, const float* __restrict__ b2,
    const float* __restrict__ W_out, const float* __restrict__ b_out,
    float* __restrict__ out)
{
    const int bi = blockIdx.x;
    const int w  = threadIdx.x >> 6;
    const int l  = threadIdx.x & 63;

    __shared__ v2f   xg0[2][CH][64];       // 16 KB
    __shared__ v2f   xg1[2][CH][64];       // 16 KB
    __shared__ v2f   xg2[2][CH][64];       // 16 KB
    __shared__ float h0r[2][CH][32];       // 4 KB
    __shared__ float h1r[2][CH][32];       // 4 KB
    __shared__ float xstage[2][CH * 64];   // 8 KB

    if (w == 0) {                          // ---- rec0 (chunk p-1) ----
        __builtin_amdgcn_s_setprio(1);
        float whA[32], whB[32];
#pragma unroll
        for (int k = 0; k < 32; ++k) {
            whA[k] = W_hh0[l * 32 + k];        KEEPV(whA[k]);
            whB[k] = W_hh0[(l + 64) * 32 + k]; KEEPV(whB[k]);
        }
        const float mt = (l < 32) ? 2.f : 1.f;
        const float ca = (l < 32) ? 1.f : 0.5f;
        const float cb = (l < 32) ? 0.f : 0.5f;
        float hs[32];
#pragma unroll
        for (int k = 0; k < 32; ++k) hs[k] = 0.f;
        float c = 0.f, hreg = 0.f;
        __syncthreads();
        for (int p = 0; p < NPHASE; ++p) {
            const int ci = p - 1;
            if (ci >= 0 && ci < NCHUNK)
                rec_chunk_rl<true>(l, &xg0[ci & 1][0][0], &h0r[ci & 1][0][0],
                                   whA, whB, hs, c, hreg, mt, ca, cb);
            __syncthreads();
        }
    } else if (w == 1) {                   // ---- rec1 (chunk p-3) ----
        __builtin_amdgcn_s_setprio(1);
        float whA[32], whB[32];
#pragma unroll
        for (int k = 0; k < 32; ++k) {
            whA[k] = W_hh1[l * 32 + k];        KEEPV(whA[k]);
            whB[k] = W_hh1[(l + 64) * 32 + k]; KEEPV(whB[k]);
        }
        const float mt = (l < 32) ? 2.f : 1.f;
        const float ca = (l < 32) ? 1.f : 0.5f;
        const float cb = (l < 32) ? 0.f : 0.5f;
        float hs[32];
#pragma unroll
        for (int k = 0; k < 32; ++k) hs[k] = 0.f;
        float c = 0.f, hreg = 0.f;
        __syncthreads();
        for (int p = 0; p < NPHASE; ++p) {
            const int ci = p - 3;
            if (ci >= 0 && ci < NCHUNK)
                rec_chunk_rl<true>(l, &xg1[ci & 1][0][0], &h1r[ci & 1][0][0],
                                   whA, whB, hs, c, hreg, mt, ca, cb);
            __syncthreads();
        }
    } else if (w == 2) {                   // ---- rec2 (chunk p-5) + projection ----
        __builtin_amdgcn_s_setprio(1);
        float whA[32], whB[32];
#pragma unroll
        for (int k = 0; k < 32; ++k) {
            whA[k] = W_hh2[l * 32 + k];        KEEPV(whA[k]);
            whB[k] = W_hh2[(l + 64) * 32 + k]; KEEPV(whB[k]);
        }
        const float mt = (l < 32) ? 2.f : 1.f;
        const float ca = (l < 32) ? 1.f : 0.5f;
        const float cb = (l < 32) ? 0.f : 0.5f;
        const float woutv = W_out[l & 31];
        float hs[32];
#pragma unroll
        for (int k = 0; k < 32; ++k) hs[k] = 0.f;
        float c = 0.f, hreg = 0.f;
        __syncthreads();
        for (int p = 0; p < NPHASE; ++p) {
            const int ci = p - 5;
            if (ci >= 0 && ci < NCHUNK)
                rec_chunk_rl<false>(l, &xg2[ci & 1][0][0], nullptr,
                                    whA, whB, hs, c, hreg, mt, ca, cb);
            __syncthreads();
        }
        float s = (l < 32) ? hreg * woutv : 0.f;
#pragma unroll
        for (int off = 16; off; off >>= 1) s += __shfl_xor(s, off);
        if (l == 0) out[bi] = s + b_out[0];
    } else if (w == 3) {                   // ---- f0: xg0 from x (chunk p) ----
        v2f wA[32], wB[32];
        const v2f* pA = reinterpret_cast<const v2f*>(W_ih0 + l * 64);
        const v2f* pB = reinterpret_cast<const v2f*>(W_ih0 + (l + 64) * 64);
#pragma unroll
        for (int i = 0; i < 32; ++i) { wA[i] = pA[i]; KEEPV(wA[i]); wB[i] = pB[i]; KEEPV(wB[i]); }
        const float bAv = b0[l], bBv = b0[l + 64];
        const float* src = x + (size_t)bi * T_SEQ * 64;
        // prologue: stage chunk 0 (initial barrier drains vmcnt)
#pragma unroll
        for (int i = 0; i < 4; ++i)
            GLOAD_LDS16(src + i * 256 + l * 4, &xstage[0][i * 256 + l * 4]);
        __syncthreads();
        for (int p = 0; p < NPHASE; ++p) {
            if (p + 1 < NCHUNK) {          // prefetch next chunk (resident by next barrier)
                const float* ns = src + (size_t)(p + 1) * CH * 64;
                float* dst = &xstage[(p + 1) & 1][0];
#pragma unroll
                for (int i = 0; i < 4; ++i)
                    GLOAD_LDS16(ns + i * 256 + l * 4, dst + i * 256 + l * 4);
            }
            if (p < NCHUNK)
                feed0_chunk(l, xstage[p & 1], &xg0[p & 1][0][0], wA, wB, bAv, bBv);
            __syncthreads();
        }
    } else if (w == 4) {                   // ---- f1: xg1 from h0 ring (chunk p-2) ----
        v2f wA[16], wB[16];
        const v2f* pA = reinterpret_cast<const v2f*>(W_ih1 + l * 32);
        const v2f* pB = reinterpret_cast<const v2f*>(W_ih1 + (l + 64) * 32);
#pragma unroll
        for (int i = 0; i < 16; ++i) { wA[i] = pA[i]; KEEPV(wA[i]); wB[i] = pB[i]; KEEPV(wB[i]); }
        const float bAv = b1[l], bBv = b1[l + 64];
        __syncthreads();
        for (int p = 0; p < NPHASE; ++p) {
            const int ci = p - 2;
            if (ci >= 0 && ci < NCHUNK)
                feed_h_chunk(l, &h0r[ci & 1][0][0], &xg1[ci & 1][0][0], wA, wB, bAv, bBv);
            __syncthreads();
        }
    } else {                               // ---- f2: xg2 from h1 ring (chunk p-4) ----
        v2f wA[16], wB[16];
        const v2f* pA = reinterpret_cast<const v2f*>(W_ih2 + l * 32);
        const v2f* pB = reinterpret_cast<const v2f*>(W_ih2 + (l + 64) * 32);
#pragma unroll
        for (int i = 0; i < 16; ++i) { wA[i] = pA[i]; KEEPV(wA[i]); wB[i] = pB[i]; KEEPV(wB[i]); }
        const float bAv = b2[l], bBv = b2[l + 64];
        __syncthreads();
        for (int p = 0; p < NPHASE; ++p) {
            const int ci = p - 4;
            if (ci >= 0 && ci < NCHUNK)
                feed_h_chunk(l, &h1r[ci & 1][0][0], &xg2[ci & 1][0][0], wA, wB, bAv, bBv);
            __syncthreads();
        }
    }
}

extern "C" void kernel_launch(void* const* d_in, const int* in_sizes, int n_in,
                              void* d_out, int out_size, void* d_ws, size_t ws_size,
                              hipStream_t stream) {
    const float* x      = (const float*)d_in[0];
    const float* W_ih0  = (const float*)d_in[1];
    const float* W_hh0  = (const float*)d_in[2];
    const float* b0     = (const float*)d_in[3];
    const float* W_ih1  = (const float*)d_in[4];
    const float* W_hh1  = (const float*)d_in[5];
    const float* b1     = (const float*)d_in[6];
    const float* W_ih2  = (const float*)d_in[7];
    const float* W_hh2  = (const float*)d_in[8];
    const float* b2     = (const float*)d_in[9];
    const float* W_out  = (const float*)d_in[10];
    const float* b_out  = (const float*)d_in[11];

    lstm3_rl_kernel<<<256, 384, 0, stream>>>(x,
                                             W_ih0, W_hh0, b0,
                                             W_ih1, W_hh1, b1,
                                             W_ih2, W_hh2, b2,
                                             W_out, b_out,
                                             (float*)d_out);
}